// Round 7
// baseline (116.255 us; speedup 1.0000x reference)
//
#include <hip/hip_runtime.h>
#include <stdint.h>

// RBF layer: out[b,c] = exp(-gamma * sqrt(max(||x_b||^2 - 2 x_b.c_c + ||c_c||^2, 0)))
// B=16384, D=1024, C=2048 (fp32 in/out).
// bf16 MFMA GEMM, 256x256 tile, BK=32, 32x32x16 MFMA, ONE phase per K-tile:
// 12 ds_reads + 4 stage gloads -> barrier -> counted lgkmcnt(6)/(0) inside the
// MFMA cluster -> counted vmcnt(4) -> barrier. 3-buffer LDS ring (2-tile
// lookahead), slot-rotation swizzle via pre-swizzled global source.
// R7 FIX vs r6: fragment ds_read row stride is 32 rows x 64 B = 2048 B
// (r6 wrongly used 4096 -> read wrong rows / past the B tile -> absmax 1.0).
// fp32 row-norms from original data; fused sqrt/exp epilogue.

typedef __attribute__((ext_vector_type(8))) short bf16x8;
typedef __attribute__((ext_vector_type(16))) float f32x16;

#define BM 256
#define BN 256
#define BK 32

__device__ __forceinline__ unsigned short f2bf(float f) {
  union { float f; unsigned int u; } c; c.f = f;
  unsigned int u = c.u;
  unsigned int r = (u + 0x7fffu + ((u >> 16) & 1u)) >> 16;  // RNE
  return (unsigned short)r;
}

// One block per row: fp32 -> bf16 convert + fp32 sum-of-squares.
__global__ __launch_bounds__(256) void prep_rows(
    const float* __restrict__ in, unsigned short* __restrict__ ob,
    float* __restrict__ norm, int K) {
  int row = blockIdx.x;
  const float4* rp = (const float4*)(in + (size_t)row * K);
  ushort4* op = (ushort4*)(ob + (size_t)row * K);
  float s = 0.f;
  for (int i = threadIdx.x; i < (K >> 2); i += blockDim.x) {
    float4 v = rp[i];
    s += v.x * v.x + v.y * v.y + v.z * v.z + v.w * v.w;
    ushort4 u;
    u.x = f2bf(v.x); u.y = f2bf(v.y); u.z = f2bf(v.z); u.w = f2bf(v.w);
    op[i] = u;
  }
  for (int off = 32; off > 0; off >>= 1) s += __shfl_down(s, off, 64);
  __shared__ float partial[4];
  int lane = threadIdx.x & 63, wv = threadIdx.x >> 6;
  if (lane == 0) partial[wv] = s;
  __syncthreads();
  if (threadIdx.x == 0) {
    float t = 0.f;
    int nw = (blockDim.x + 63) >> 6;
    for (int w = 0; w < nw; ++w) t += partial[w];
    norm[row] = t;
  }
}

#define GLDS(gptr, lptr)                                                      \
  __builtin_amdgcn_global_load_lds(                                           \
      (const __attribute__((address_space(1))) unsigned int*)(gptr),          \
      (__attribute__((address_space(3))) unsigned int*)(lptr), 16, 0, 0)

#define DSR(dst, addr, imm)                                                   \
  asm volatile("ds_read_b128 %0, %1 offset:%c2"                              \
               : "=v"(dst) : "v"(addr), "i"(imm))

#define WAIT_LGKM(n)                                                          \
  do {                                                                        \
    asm volatile("s_waitcnt lgkmcnt(" #n ")" ::: "memory");                   \
    __builtin_amdgcn_sched_barrier(0);                                        \
  } while (0)

#define MFMA32(a, b, c) __builtin_amdgcn_mfma_f32_32x32x16_bf16((a), (b), (c), 0, 0, 0)

// 256x256 bf16 GEMM, 32x32x16 MFMA, 1 phase/K-tile, 3-buffer counted-vmcnt
// ring + fused RBF epilogue. A: [M][K] bf16 (x). Bm: [N][K] bf16 (centers).
__global__ __launch_bounds__(512, 2) void rbf_gemm(
    const unsigned short* __restrict__ A, const unsigned short* __restrict__ Bm,
    const float* __restrict__ x2, const float* __restrict__ c2,
    const float* __restrict__ gamma, float* __restrict__ out,
    int M, int N, int K) {
  // 3 buffers x 32KB: A-tile 16KB (256x32 bf16) then B-tile 16KB.
  // Physical 16B slot p of row r holds logical slot l where p=(l+(r>>1))&3.
  __shared__ __align__(16) unsigned short lds[3 * 16384];

  int nbn = N / BN;
  int nwg = (M / BM) * nbn;
  int bid = blockIdx.x;
  int wg = bid;
  if ((nwg & 7) == 0) {  // XCD-aware swizzle (bijective: nwg % 8 == 0)
    int cpx = nwg >> 3;
    wg = (bid & 7) * cpx + (bid >> 3);
  }
  int bm = wg / nbn, bn = wg % nbn;

  int tid = threadIdx.x;
  int lane = tid & 63, wv = tid >> 6;
  int wm = wv >> 1;   // 0..3 : wave row (64 A-rows each)
  int wn = wv & 1;    // 0..1 : wave col (128 B-rows each)
  int l31 = lane & 31, l5 = lane >> 5;

  // ---- staging map: each gload inst covers 128 rows x 32 cols (8KB) ----
  int lsw = ((tid & 3) - (tid >> 3)) & 3;  // pre-swizzled logical 16B slot
  const unsigned short* AgT =
      A + (size_t)bm * BM * K + (size_t)(tid >> 2) * K + lsw * 8;
  const unsigned short* BgT =
      Bm + (size_t)bn * BN * K + (size_t)(tid >> 2) * K + lsw * 8;
  size_t rstep = (size_t)128 * K;

  // ---- fragment read map (32x32x16: A row=l&31, k=(l>>5)*8+j) ----
  // logical slot = ks*2 + l5 ; phys slot = (logical + ((l31>>1)&3)) & 3.
  // ks=0 -> pA0 ; ks=1 -> pA0^2 (addr ^ 32 bytes).
  int pA0 = (l5 + ((l31 >> 1) & 3)) & 3;
  unsigned aByte = (unsigned)((wm * 64 + l31) * 64 + pA0 * 16);
  unsigned bByte = (unsigned)(16384 + (wn * 128 + l31) * 64 + pA0 * 16);
  unsigned ldsBase =
      (unsigned)(size_t)(const __attribute__((address_space(3))) void*)&lds[0];

  f32x16 c00 = {0}, c01 = {0}, c02 = {0}, c03 = {0};
  f32x16 c10 = {0}, c11 = {0}, c12 = {0}, c13 = {0};

  int nt = K / BK;

  // ---- prologue: stage tiles 0,1 into buffers 0,1 ----
#pragma unroll
  for (int tt = 0; tt < 2; ++tt) {
    unsigned short* base = lds + tt * 16384;
    GLDS(AgT + (size_t)tt * BK, base + tid * 8);
    GLDS(AgT + rstep + (size_t)tt * BK, base + 4096 + tid * 8);
    GLDS(BgT + (size_t)tt * BK, base + 8192 + tid * 8);
    GLDS(BgT + rstep + (size_t)tt * BK, base + 12288 + tid * 8);
  }
  asm volatile("s_waitcnt vmcnt(4)" ::: "memory");  // tile 0 resident
  __builtin_amdgcn_s_barrier();

  int rb = 0;
  for (int t = 0; t < nt; ++t) {
    unsigned bufOff = (unsigned)rb * 32768u;
    int sbi = rb + 2; if (sbi >= 3) sbi -= 3;      // stage target (t+2)
    unsigned short* bufS = lds + sbi * 16384;
    size_t ktS = (size_t)(t + 2) * BK;
    bool doStage = (t + 2 < nt);

    unsigned aAd = ldsBase + bufOff + aByte;       // ks=0 addresses
    unsigned bAd = ldsBase + bufOff + bByte;
    unsigned aAd1 = aAd ^ 32u;                     // ks=1 (phys slot ^ 2)
    unsigned bAd1 = bAd ^ 32u;

    // ---- issue all 12 fragment reads (k0 set first), then 4 stage gloads
    // Fragment row stride: 32 rows x 64 B = 2048 B.   (r7 fix)
    bf16x8 a0, a1, b0, b1, b2, b3, a0k, a1k, b0k, b1k, b2k, b3k;
    DSR(a0, aAd, 0);      DSR(a1, aAd, 2048);
    DSR(b0, bAd, 0);      DSR(b1, bAd, 2048);
    DSR(b2, bAd, 4096);   DSR(b3, bAd, 6144);
    DSR(a0k, aAd1, 0);    DSR(a1k, aAd1, 2048);
    DSR(b0k, bAd1, 0);    DSR(b1k, bAd1, 2048);
    DSR(b2k, bAd1, 4096); DSR(b3k, bAd1, 6144);
    if (doStage) {
      GLDS(AgT + ktS, bufS + tid * 8);
      GLDS(AgT + rstep + ktS, bufS + 4096 + tid * 8);
      GLDS(BgT + ktS, bufS + 8192 + tid * 8);
      GLDS(BgT + rstep + ktS, bufS + 12288 + tid * 8);
    }
    __builtin_amdgcn_s_barrier();   // reads drain while waves sync

    WAIT_LGKM(6);                   // k0 set (first 6 reads) resident
    __builtin_amdgcn_s_setprio(1);
    c00 = MFMA32(a0, b0, c00);
    c01 = MFMA32(a0, b1, c01);
    c02 = MFMA32(a0, b2, c02);
    c03 = MFMA32(a0, b3, c03);
    c10 = MFMA32(a1, b0, c10);
    c11 = MFMA32(a1, b1, c11);
    c12 = MFMA32(a1, b2, c12);
    c13 = MFMA32(a1, b3, c13);
    WAIT_LGKM(0);                   // k1 set resident
    c00 = MFMA32(a0k, b0k, c00);
    c01 = MFMA32(a0k, b1k, c01);
    c02 = MFMA32(a0k, b2k, c02);
    c03 = MFMA32(a0k, b3k, c03);
    c10 = MFMA32(a1k, b0k, c10);
    c11 = MFMA32(a1k, b1k, c11);
    c12 = MFMA32(a1k, b2k, c12);
    c13 = MFMA32(a1k, b3k, c13);
    __builtin_amdgcn_s_setprio(0);

    // Counted wait: outstanding = S_{t+1}(4) + S_{t+2}(4); vmcnt(4) => t+1 ready.
    if (t < nt - 2) {
      asm volatile("s_waitcnt vmcnt(4)" ::: "memory");
    } else if (t == nt - 2) {
      asm volatile("s_waitcnt vmcnt(0)" ::: "memory");
    }
    if (t < nt - 1) __builtin_amdgcn_s_barrier();

    rb++; if (rb == 3) rb = 0;
  }

  // ---- epilogue: 32x32 C/D layout col=lane&31, row=(reg&3)+8*(reg>>2)+4*(lane>>5)
  float g = gamma[0];
  int rowb = bm * BM + wm * 64 + 4 * l5;
  int colb = bn * BN + wn * 128 + l31;
#define EPI(cv, f, n)                                                         \
  _Pragma("unroll")                                                           \
  for (int reg = 0; reg < 16; ++reg) {                                        \
    int row = rowb + (f) * 32 + (reg & 3) + 8 * (reg >> 2);                   \
    int col = colb + (n) * 32;                                                \
    float sq = fmaxf(x2[row] + c2[col] - 2.f * (cv)[reg], 0.f);               \
    out[(size_t)row * N + col] = __expf(-g * __builtin_sqrtf(sq));            \
  }
  EPI(c00, 0, 0) EPI(c01, 0, 1) EPI(c02, 0, 2) EPI(c03, 0, 3)
  EPI(c10, 1, 0) EPI(c11, 1, 1) EPI(c12, 1, 2) EPI(c13, 1, 3)
#undef EPI
}

// Correctness fallback if workspace/shape doesn't fit (slow, fp32 vector path).
__global__ __launch_bounds__(256) void rbf_naive(
    const float* __restrict__ x, const float* __restrict__ cent,
    const float* __restrict__ gamma, float* __restrict__ out, int D, int N) {
  int row = blockIdx.x;
  int col = blockIdx.y * blockDim.x + threadIdx.x;
  extern __shared__ float xs[];
  for (int i = threadIdx.x; i < D; i += blockDim.x)
    xs[i] = x[(size_t)row * D + i];
  __syncthreads();
  if (col >= N) return;
  const float* cp = cent + (size_t)col * D;
  float s = 0.f;
  for (int d = 0; d < D; ++d) {
    float df = xs[d] - cp[d];
    s += df * df;
  }
  out[(size_t)row * N + col] = __expf(-gamma[0] * __builtin_sqrtf(fmaxf(s, 0.f)));
}

extern "C" void kernel_launch(void* const* d_in, const int* in_sizes, int n_in,
                              void* d_out, int out_size, void* d_ws, size_t ws_size,
                              hipStream_t stream) {
  const float* x = (const float*)d_in[0];
  const float* cent = (const float*)d_in[1];
  const float* gamma = (const float*)d_in[2];
  float* out = (float*)d_out;

  const int D = 1024;  // feature dim per the reference
  int Brows = in_sizes[0] / D;
  int C = in_sizes[1] / D;

  size_t xb_bytes = (size_t)Brows * D * 2;
  size_t cb_bytes = (size_t)C * D * 2;
  size_t need = xb_bytes + cb_bytes + (size_t)Brows * 4 + (size_t)C * 4;
  bool can = (ws_size >= need) && (Brows % BM == 0) && (C % BN == 0) &&
             (D % BK == 0) && (D / BK >= 3);

  if (!can) {
    dim3 grid(Brows, (C + 255) / 256);
    hipLaunchKernelGGL(rbf_naive, grid, dim3(256), D * sizeof(float), stream,
                       x, cent, gamma, out, D, C);
    return;
  }

  unsigned short* xb = (unsigned short*)d_ws;
  unsigned short* cb = (unsigned short*)((char*)d_ws + xb_bytes);
  float* x2 = (float*)((char*)d_ws + xb_bytes + cb_bytes);
  float* c2 = x2 + Brows;

  hipLaunchKernelGGL(prep_rows, dim3(Brows), dim3(256), 0, stream, x, xb, x2, D);
  hipLaunchKernelGGL(prep_rows, dim3(C), dim3(256), 0, stream, cent, cb, c2, D);

  int nwg = (Brows / BM) * (C / BN);
  hipLaunchKernelGGL(rbf_gemm, dim3(nwg), dim3(512), 0, stream,
                     xb, cb, x2, c2, gamma, out, Brows, C, D);
}

// Round 8
// 103.323 us; speedup vs baseline: 1.1252x; 1.1252x over previous
//
#include <hip/hip_runtime.h>
#include <stdint.h>

// RBF layer: out[b,c] = exp(-gamma * sqrt(max(||x_b||^2 - 2 x_b.c_c + ||c_c||^2, 0)))
// B=16384, D=1024, C=2048 (fp32 in/out).
// R8: faithful m201-style 8-phase schedule. 256x256 tile, BK=64, 16x16x32 MFMA,
// 8 waves (2M x 4N), per-wave 128x64 output. 2 LDS buffers (tile parity-fixed),
// 8 phases / 2 K-tiles: {ds_reads -> 1 half-tile stage -> barrier -> lgkmcnt(0)
// +sched_barrier -> setprio(1) 16 MFMA setprio(0) -> barrier}, vmcnt(4) only at
// end of P4 and P8. XOR swizzle slot^=(row&7) via pre-swizzled global source.
// fp32 row-norms from original data; fused sqrt/exp epilogue.

typedef __attribute__((ext_vector_type(8))) short bf16x8;
typedef __attribute__((ext_vector_type(4))) float f32x4;

#define BM 256
#define BN 256
#define BK 64

__device__ __forceinline__ unsigned short f2bf(float f) {
  union { float f; unsigned int u; } c; c.f = f;
  unsigned int u = c.u;
  unsigned int r = (u + 0x7fffu + ((u >> 16) & 1u)) >> 16;  // RNE
  return (unsigned short)r;
}

__global__ __launch_bounds__(256) void prep_rows(
    const float* __restrict__ in, unsigned short* __restrict__ ob,
    float* __restrict__ norm, int K) {
  int row = blockIdx.x;
  const float4* rp = (const float4*)(in + (size_t)row * K);
  ushort4* op = (ushort4*)(ob + (size_t)row * K);
  float s = 0.f;
  for (int i = threadIdx.x; i < (K >> 2); i += blockDim.x) {
    float4 v = rp[i];
    s += v.x * v.x + v.y * v.y + v.z * v.z + v.w * v.w;
    ushort4 u;
    u.x = f2bf(v.x); u.y = f2bf(v.y); u.z = f2bf(v.z); u.w = f2bf(v.w);
    op[i] = u;
  }
  for (int off = 32; off > 0; off >>= 1) s += __shfl_down(s, off, 64);
  __shared__ float partial[4];
  int lane = threadIdx.x & 63, wv = threadIdx.x >> 6;
  if (lane == 0) partial[wv] = s;
  __syncthreads();
  if (threadIdx.x == 0) {
    float t = 0.f;
    int nw = (blockDim.x + 63) >> 6;
    for (int w = 0; w < nw; ++w) t += partial[w];
    norm[row] = t;
  }
}

#define GLDS(gptr, lptr)                                                      \
  __builtin_amdgcn_global_load_lds(                                           \
      (const __attribute__((address_space(1))) unsigned int*)(gptr),          \
      (__attribute__((address_space(3))) unsigned int*)(lptr), 16, 0, 0)

#define DSR(dst, addr, imm)                                                   \
  asm volatile("ds_read_b128 %0, %1 offset:%c2"                              \
               : "=v"(dst) : "v"(addr), "i"(imm))

#define BARRIER __builtin_amdgcn_s_barrier()
#define LGKM0                                                                 \
  do {                                                                        \
    asm volatile("s_waitcnt lgkmcnt(0)" ::: "memory");                        \
    __builtin_amdgcn_sched_barrier(0);                                        \
  } while (0)

#define MFMA16(a, b, c) __builtin_amdgcn_mfma_f32_16x16x32_bf16((a), (b), (c), 0, 0, 0)

__global__ __launch_bounds__(512, 1) void rbf_gemm(
    const unsigned short* __restrict__ A, const unsigned short* __restrict__ Bm,
    const float* __restrict__ x2, const float* __restrict__ c2,
    const float* __restrict__ gamma, float* __restrict__ out,
    int M, int N, int K) {
  __shared__ __align__(128) unsigned short lds[2 * 32768];

  int nbn = N / BN;
  int nwg = (M / BM) * nbn;
  int bid = blockIdx.x;
  int wg = bid;
  if ((nwg & 7) == 0) {
    int cpx = nwg >> 3;
    wg = (bid & 7) * cpx + (bid >> 3);
  }
  int bm = wg / nbn, bn = wg % nbn;

  int tid = threadIdx.x;
  int lane = tid & 63, wv = tid >> 6;
  int wm = wv >> 2;   // 0..1
  int wn = wv & 3;    // 0..3
  int l15 = lane & 15, l4 = lane >> 4;

  const size_t Ksz = (size_t)K;

  int lsw = (tid & 7) ^ ((tid >> 3) & 7);
  const unsigned short* AgT = A + (size_t)bm * BM * Ksz + (size_t)(tid >> 3) * Ksz + lsw * 8;
  const unsigned short* BgT = Bm + (size_t)bn * BN * Ksz + (size_t)(tid >> 3) * Ksz + lsw * 8;
  unsigned short* buf0 = lds;
  unsigned short* buf1 = lds + 32768;

#define STG_A(TAU, H, BUFS)                                                   \
  do {                                                                        \
    GLDS(AgT + (size_t)((H)*128) * Ksz + (size_t)(TAU)*64, (BUFS) + (H)*8192 + tid * 8);          \
    GLDS(AgT + (size_t)((H)*128 + 64) * Ksz + (size_t)(TAU)*64, (BUFS) + (H)*8192 + 4096 + tid * 8); \
  } while (0)
#define STG_B(TAU, H, BUFS)                                                   \
  do {                                                                        \
    GLDS(BgT + (size_t)((H)*128) * Ksz + (size_t)(TAU)*64, (BUFS) + 16384 + (H)*8192 + tid * 8);  \
    GLDS(BgT + (size_t)((H)*128 + 64) * Ksz + (size_t)(TAU)*64, (BUFS) + 16384 + (H)*8192 + 4096 + tid * 8); \
  } while (0)

  int slot0 = l4 ^ (l15 & 7);
  unsigned ldsBase =
      (unsigned)(size_t)(const __attribute__((address_space(3))) void*)&lds[0];
  unsigned aAd0_0 = ldsBase + (unsigned)((wm * 128 + l15) * 128 + slot0 * 16);
  unsigned aAd1_0 = aAd0_0 ^ 64u;
  unsigned aAd0_1 = aAd0_0 + 65536u;
  unsigned aAd1_1 = aAd1_0 + 65536u;
  unsigned bAd0_0 = ldsBase + (unsigned)(32768 + (wn * 64 + l15) * 128 + slot0 * 16);
  unsigned bAd1_0 = bAd0_0 ^ 64u;
  unsigned bAd0_1 = bAd0_0 + 65536u;
  unsigned bAd1_1 = bAd1_0 + 65536u;

  bf16x8 aF[8][2], bF[4][2];
  f32x4 acc[8][4];
#pragma unroll
  for (int m = 0; m < 8; ++m)
#pragma unroll
    for (int n = 0; n < 4; ++n) acc[m][n] = (f32x4){0.f, 0.f, 0.f, 0.f};

#define READ_A4(MB, A0, A1)                                                   \
  DSR(aF[(MB) + 0][0], A0, ((MB) + 0) * 2048);                                \
  DSR(aF[(MB) + 1][0], A0, ((MB) + 1) * 2048);                                \
  DSR(aF[(MB) + 2][0], A0, ((MB) + 2) * 2048);                                \
  DSR(aF[(MB) + 3][0], A0, ((MB) + 3) * 2048);                                \
  DSR(aF[(MB) + 0][1], A1, ((MB) + 0) * 2048);                                \
  DSR(aF[(MB) + 1][1], A1, ((MB) + 1) * 2048);                                \
  DSR(aF[(MB) + 2][1], A1, ((MB) + 2) * 2048);                                \
  DSR(aF[(MB) + 3][1], A1, ((MB) + 3) * 2048);
#define READ_B2(NB, B0, B1)                                                   \
  DSR(bF[(NB) + 0][0], B0, ((NB) + 0) * 2048);                                \
  DSR(bF[(NB) + 1][0], B0, ((NB) + 1) * 2048);                                \
  DSR(bF[(NB) + 0][1], B1, ((NB) + 0) * 2048);                                \
  DSR(bF[(NB) + 1][1], B1, ((NB) + 1) * 2048);

#define QUAD(MB, NB)                                                          \
  do {                                                                        \
    _Pragma("unroll") for (int m_ = (MB); m_ < (MB) + 4; ++m_) {              \
      _Pragma("unroll") for (int n_ = (NB); n_ < (NB) + 2; ++n_) {            \
        acc[m_][n_] = MFMA16(aF[m_][0], bF[n_][0], acc[m_][n_]);              \
        acc[m_][n_] = MFMA16(aF[m_][1], bF[n_][1], acc[m_][n_]);              \
      }                                                                       \
    }                                                                         \
  } while (0)

#define PRIO1 __builtin_amdgcn_s_setprio(1)
#define PRIO0 __builtin_amdgcn_s_setprio(0)

  int nt = K / BK;
  int NI = nt / 2;

  STG_B(0, 0, buf0); STG_B(0, 1, buf0);
  STG_A(0, 0, buf0); STG_A(0, 1, buf0);
  STG_B(1, 0, buf1); STG_B(1, 1, buf1);
  asm volatile("s_waitcnt vmcnt(4)" ::: "memory");
  BARRIER;

  for (int i = 0; i < NI; ++i) {
    int t1 = 2 * i + 1;
    int t0s = 2 * i + 2, t1s = 2 * i + 3;
    bool g2 = (i < NI - 1);

    // ============ K-tile t0 (buf0) ============
    READ_A4(0, aAd0_0, aAd1_0);
    READ_B2(0, bAd0_0, bAd1_0);
    STG_A(t1, 0, buf1);
    BARRIER; LGKM0;
    PRIO1; QUAD(0, 0); PRIO0;
    BARRIER;

    READ_B2(2, bAd0_0, bAd1_0);
    STG_A(t1, 1, buf1);
    BARRIER; LGKM0;
    PRIO1; QUAD(0, 2); PRIO0;
    BARRIER;

    READ_A4(4, aAd0_0, aAd1_0);
    READ_B2(0, bAd0_0, bAd1_0);
    if (g2) STG_B(t0s, 0, buf0);
    BARRIER; LGKM0;
    PRIO1; QUAD(4, 0); PRIO0;
    BARRIER;

    if (g2) STG_B(t0s, 1, buf0);
    BARRIER; LGKM0;
    PRIO1; QUAD(4, 2); PRIO0;
    if (g2) {
      asm volatile("s_waitcnt vmcnt(4)" ::: "memory");
    } else {
      asm volatile("s_waitcnt vmcnt(0)" ::: "memory");
    }
    BARRIER;

    // ============ K-tile t1 (buf1) ============
    READ_A4(0, aAd0_1, aAd1_1);
    READ_B2(0, bAd0_1, bAd1_1);
    if (g2) STG_A(t0s, 0, buf0);
    BARRIER; LGKM0;
    PRIO1; QUAD(0, 0); PRIO0;
    BARRIER;

    READ_B2(2, bAd0_1, bAd1_1);
    if (g2) STG_A(t0s, 1, buf0);
    BARRIER; LGKM0;
    PRIO1; QUAD(0, 2); PRIO0;
    BARRIER;

    READ_A4(4, aAd0_1, aAd1_1);
    READ_B2(0, bAd0_1, bAd1_1);
    if (g2) STG_B(t1s, 0, buf1);
    BARRIER; LGKM0;
    PRIO1; QUAD(4, 0); PRIO0;
    BARRIER;

    if (g2) STG_B(t1s, 1, buf1);
    BARRIER; LGKM0;
    PRIO1; QUAD(4, 2); PRIO0;
    if (g2) {
      asm volatile("s_waitcnt vmcnt(4)" ::: "memory");
      BARRIER;
    }
  }

  float g = gamma[0];
  int rb0 = bm * BM + wm * 128 + l4 * 4;
  int cb0 = bn * BN + wn * 64 + l15;
#pragma unroll
  for (int m = 0; m < 8; ++m) {
#pragma unroll
    for (int j = 0; j < 4; ++j) {
      int row = rb0 + m * 16 + j;
      float xr = x2[row];
      size_t ob = (size_t)row * N;
#pragma unroll
      for (int n = 0; n < 4; ++n) {
        int col = cb0 + n * 16;
        float sq = fmaxf(xr + c2[col] - 2.f * acc[m][n][j], 0.f);
        out[ob + col] = __expf(-g * __builtin_sqrtf(sq));
      }
    }
  }
}

__global__ __launch_bounds__(256) void rbf_naive(
    const float* __restrict__ x, const float* __restrict__ cent,
    const float* __restrict__ gamma, float* __restrict__ out, int D, int N) {
  int row = blockIdx.x;
  int col = blockIdx.y * blockDim.x + threadIdx.x;
  extern __shared__ float xs[];
  for (int i = threadIdx.x; i < D; i += blockDim.x)
    xs[i] = x[(size_t)row * D + i];
  __syncthreads();
  if (col >= N) return;
  const float* cp = cent + (size_t)col * D;
  float s = 0.f;
  for (int d = 0; d < D; ++d) {
    float df = xs[d] - cp[d];
    s += df * df;
  }
  out[(size_t)row * N + col] = __expf(-gamma[0] * __builtin_sqrtf(fmaxf(s, 0.f)));
}

extern "C" void kernel_launch(void* const* d_in, const int* in_sizes, int n_in,
                              void* d_out, int out_size, void* d_ws, size_t ws_size,
                              hipStream_t stream) {
  const float* x = (const float*)d_in[0];
  const float* cent = (const float*)d_in[1];
  const float* gamma = (const float*)d_in[2];
  float* out = (float*)d_out;

  const int D = 1024;
  int Brows = in_sizes[0] / D;
  int C = in_sizes[1] / D;

  size_t xb_bytes = (size_t)Brows * D * 2;
  size_t cb_bytes = (size_t)C * D * 2;
  size_t need = xb_bytes + cb_bytes + (size_t)Brows * 4 + (size_t)C * 4;
  bool can = (ws_size >= need) && (Brows % BM == 0) && (C % BN == 0) &&
             (D % 128 == 0) && (D / BK >= 4);

  if (!can) {
    dim3 grid(Brows, (C + 255) / 256);
    hipLaunchKernelGGL(rbf_naive, grid, dim3(256), D * sizeof(float), stream,
                       x, cent, gamma, out, D, C);
    return;
  }

  unsigned short* xb = (unsigned short*)d_ws;
  unsigned short* cb = (unsigned short*)((char*)d_ws + xb_bytes);
  float* x2 = (float*)((char*)d_ws + xb_bytes + cb_bytes);
  float* c2 = x2 + Brows;

  hipLaunchKernelGGL(prep_rows, dim3(Brows), dim3(256), 0, stream, x, xb, x2, D);
  hipLaunchKernelGGL(prep_rows, dim3(C), dim3(256), 0, stream, cent, cb, c2, D);

  int nwg = (Brows / BM) * (C / BN);
  hipLaunchKernelGGL(rbf_gemm, dim3(nwg), dim3(512), 0, stream,
                     xb, cb, x2, c2, gamma, out, Brows, C, D);
}